// Round 7
// baseline (805.374 us; speedup 1.0000x reference)
//
#include <hip/hip_runtime.h>
#include <math.h>

#define N_NODES 100000
#define DIM 64
#define N_EDGES 1600000

#define NBF 782         // fine buckets: col >> 7 (ceil(100000/128) = 782)
#define BK_NODES 128
#define CAP 3072        // per-bucket capacity (mean 2046, sigma ~45 -> >20 sigma)

#define SC_CHUNK 8192
#define SC_BLOCKS ((N_EDGES + SC_CHUNK - 1) / SC_CHUNK)  // 196

#define LIN_BLOCKS 1563 // ceil(6250 waves / 4 per block); 16 rows/wave

typedef _Float16 half8 __attribute__((ext_vector_type(8)));
typedef _Float16 half4 __attribute__((ext_vector_type(4)));
typedef float f32x4 __attribute__((ext_vector_type(4)));

// ---------------------------------------------------------------------------
// GEMM: MFMA f16 [16 x 64] @ [64 x 128] per wave.
//   C cols 0..63  -> Mh (f16) = x@Wm + bm ; es = exp(mean_row(M))
//   C cols 64..127-> out (f32) = x@Wr + br
// ---------------------------------------------------------------------------
__global__ __launch_bounds__(256) void k_gemm(
        const float* __restrict__ x,
        const float* __restrict__ Wm, const float* __restrict__ bm,
        const float* __restrict__ Wr, const float* __restrict__ br,
        _Float16* __restrict__ Mh, float* __restrict__ es,
        float* __restrict__ out) {
    const int wave = blockIdx.x * 4 + (threadIdx.x >> 6);
    if (wave >= N_NODES / 16) return;
    const int lane = threadIdx.x & 63;
    const int quad = lane >> 4;
    const int l15 = lane & 15;
    const int row0 = wave * 16;

    half8 bfrag[8][2];
#pragma unroll
    for (int ct = 0; ct < 8; ++ct) {
        const float* W = (ct < 4) ? Wm : Wr;
        const int c = (ct & 3) * 16 + l15;
#pragma unroll
        for (int kc = 0; kc < 2; ++kc) {
            half8 f;
#pragma unroll
            for (int j = 0; j < 8; ++j)
                f[j] = (_Float16)W[(kc * 32 + quad * 8 + j) * DIM + c];
            bfrag[ct][kc] = f;
        }
    }

    half8 afrag[2];
#pragma unroll
    for (int kc = 0; kc < 2; ++kc) {
        const float* xp = x + (size_t)(row0 + l15) * DIM + kc * 32 + quad * 8;
        const float4 x0 = *(const float4*)xp;
        const float4 x1 = *(const float4*)(xp + 4);
        half8 f;
        f[0] = (_Float16)x0.x; f[1] = (_Float16)x0.y;
        f[2] = (_Float16)x0.z; f[3] = (_Float16)x0.w;
        f[4] = (_Float16)x1.x; f[5] = (_Float16)x1.y;
        f[6] = (_Float16)x1.z; f[7] = (_Float16)x1.w;
        afrag[kc] = f;
    }

    f32x4 acc[8];
#pragma unroll
    for (int ct = 0; ct < 8; ++ct) {
        f32x4 a = {0.f, 0.f, 0.f, 0.f};
        a = __builtin_amdgcn_mfma_f32_16x16x32_f16(afrag[0], bfrag[ct][0], a, 0, 0, 0);
        a = __builtin_amdgcn_mfma_f32_16x16x32_f16(afrag[1], bfrag[ct][1], a, 0, 0, 0);
        acc[ct] = a;
    }

    float rsum[4] = {0.f, 0.f, 0.f, 0.f};
#pragma unroll
    for (int ct = 0; ct < 8; ++ct) {
        const float bias = (ct < 4) ? bm[(ct & 3) * 16 + l15]
                                    : br[(ct & 3) * 16 + l15];
#pragma unroll
        for (int r = 0; r < 4; ++r) {
            const float v = acc[ct][r] + bias;
            const size_t idx = (size_t)(row0 + quad * 4 + r) * DIM + (ct & 3) * 16 + l15;
            if (ct < 4) {
                Mh[idx] = (_Float16)v;
                rsum[r] += v;
            } else {
                out[idx] = v;
            }
        }
    }
#pragma unroll
    for (int o = 1; o <= 8; o <<= 1) {
#pragma unroll
        for (int r = 0; r < 4; ++r) rsum[r] += __shfl_xor(rsum[r], o, 64);
    }
    if (l15 == 0) {
#pragma unroll
        for (int r = 0; r < 4; ++r)
            es[row0 + quad * 4 + r] = __expf(rsum[r] * (1.0f / DIM));
    }
}

// ---------------------------------------------------------------------------
// Scatter: each 1024-thread block counting-sorts its 8192-edge chunk by fine
// bucket (col>>7) in LDS, reserves one global range per nonzero bin
// (aggregated atomic on cursor), writes packed edges ((row<<7)|(col&127))
// into the bucket's padded slab [bk*CAP, bk*CAP+CAP).
// ---------------------------------------------------------------------------
__global__ __launch_bounds__(1024) void k_scatter(
        const int* __restrict__ row, const int* __restrict__ col,
        int* __restrict__ cursor, unsigned int* __restrict__ pairs) {
    __shared__ int cnt[NBF];
    __shared__ int base_l[NBF];
    __shared__ int base_g[NBF];
    __shared__ int sd[1024];
    __shared__ unsigned int stage[SC_CHUNK];
    __shared__ unsigned short stage_bk[SC_CHUNK];

    const int t = threadIdx.x;
    const int start = blockIdx.x * SC_CHUNK;
    const int mEnd = min(N_EDGES, start + SC_CHUNK);

    for (int i = t; i < NBF; i += 1024) cnt[i] = 0;
    __syncthreads();

    int rr[8], cc[8], lr[8];
#pragma unroll
    for (int k = 0; k < 8; ++k) {
        const int idx = start + k * 1024 + t;
        if (idx < mEnd) {
            cc[k] = col[idx];
            rr[k] = row[idx];
            lr[k] = atomicAdd(&cnt[cc[k] >> 7], 1);
        }
    }
    __syncthreads();

    const int v = (t < NBF) ? cnt[t] : 0;
    sd[t] = v;
    __syncthreads();
    for (int o = 1; o < 1024; o <<= 1) {
        const int add = (t >= o) ? sd[t - o] : 0;
        __syncthreads();
        sd[t] += add;
        __syncthreads();
    }
    if (t < NBF) {
        base_l[t] = sd[t] - v;
        if (v > 0) base_g[t] = atomicAdd(&cursor[t], v);
    }
    __syncthreads();

#pragma unroll
    for (int k = 0; k < 8; ++k) {
        const int idx = start + k * 1024 + t;
        if (idx < mEnd) {
            const int bk = cc[k] >> 7;
            const int slot = base_l[bk] + lr[k];
            stage[slot] = ((unsigned int)rr[k] << 7) | (unsigned int)(cc[k] & 127);
            stage_bk[slot] = (unsigned short)bk;
        }
    }
    __syncthreads();

    const int m = mEnd - start;
    for (int i = t; i < m; i += 1024) {
        const int bk = stage_bk[i];
        const int gslot = base_g[bk] + (i - base_l[bk]);
        if (gslot < CAP) pairs[(size_t)bk * CAP + gslot] = stage[i];
    }
}

// ---------------------------------------------------------------------------
// Aggregate: one 512-thread block per fine bucket (128 dst nodes). LDS f32
// accumulators per node; edges processed in arbitrary order via ds_add_f32.
// Epilogue: out[n] += acc[n]/l[n].
// ---------------------------------------------------------------------------
__global__ __launch_bounds__(512) void k_aggregate(
        const unsigned int* __restrict__ pairs, const int* __restrict__ cursor,
        const float* __restrict__ es, const half4* __restrict__ Mh4,
        float* __restrict__ out) {
    __shared__ float acc[BK_NODES * DIM];  // 32 KB
    __shared__ float lsum[BK_NODES];
    const int b = blockIdx.x;
    const int t = threadIdx.x;
    const int g = t >> 4;      // group 0..31
    const int gl = t & 15;     // lane in group -> dims gl*4..gl*4+3

    for (int i = t; i < BK_NODES * DIM; i += 512) acc[i] = 0.f;
    if (t < BK_NODES) lsum[t] = 0.f;
    __syncthreads();

    const int cnt = min(cursor[b], CAP);
    const size_t base = (size_t)b * CAP;

    int i = g;
    for (; i + 32 < cnt; i += 64) {
        const unsigned int p0 = pairs[base + i];
        const unsigned int p1 = pairs[base + i + 32];
        const int c0 = (int)(p0 & 127u), s0 = (int)(p0 >> 7);
        const int c1 = (int)(p1 & 127u), s1 = (int)(p1 >> 7);
        const float w0 = es[s0];
        const float w1 = es[s1];
        const half4 m0 = Mh4[(size_t)s0 * 16 + gl];
        const half4 m1 = Mh4[(size_t)s1 * 16 + gl];
#pragma unroll
        for (int k = 0; k < 4; ++k)
            atomicAdd(&acc[c0 * DIM + gl * 4 + k], w0 * (float)m0[k]);
#pragma unroll
        for (int k = 0; k < 4; ++k)
            atomicAdd(&acc[c1 * DIM + gl * 4 + k], w1 * (float)m1[k]);
        if (gl == 0) {
            atomicAdd(&lsum[c0], w0);
            atomicAdd(&lsum[c1], w1);
        }
    }
    if (i < cnt) {
        const unsigned int p0 = pairs[base + i];
        const int c0 = (int)(p0 & 127u), s0 = (int)(p0 >> 7);
        const float w0 = es[s0];
        const half4 m0 = Mh4[(size_t)s0 * 16 + gl];
#pragma unroll
        for (int k = 0; k < 4; ++k)
            atomicAdd(&acc[c0 * DIM + gl * 4 + k], w0 * (float)m0[k]);
        if (gl == 0) atomicAdd(&lsum[c0], w0);
    }
    __syncthreads();

    for (int idx = t; idx < BK_NODES * DIM; idx += 512) {
        const int nl = idx >> 6;
        const int node = b * BK_NODES + nl;
        if (node < N_NODES) {
            const float l = lsum[nl];
            if (l > 0.f)
                out[(size_t)node * DIM + (idx & 63)] += acc[idx] / l;
        }
    }
}

// ---------------------------------------------------------------------------
extern "C" void kernel_launch(void* const* d_in, const int* in_sizes, int n_in,
                              void* d_out, int out_size, void* d_ws, size_t ws_size,
                              hipStream_t stream) {
    const float* x  = (const float*)d_in[0];
    const int*   ei = (const int*)d_in[1];
    const float* Wm = (const float*)d_in[2];
    const float* bm = (const float*)d_in[3];
    const float* Wr = (const float*)d_in[4];
    const float* br = (const float*)d_in[5];
    float* out = (float*)d_out;
    const int* row = ei;            // edge_index[0]
    const int* col = ei + N_EDGES;  // edge_index[1]

    char* ws = (char*)d_ws;
    _Float16* Mh    = (_Float16*)ws;     ws += (size_t)N_NODES * DIM * sizeof(_Float16);
    float* es       = (float*)ws;        ws += (size_t)N_NODES * sizeof(float);
    int* cursor     = (int*)ws;          ws += (size_t)1024 * sizeof(int);
    unsigned int* pairs = (unsigned int*)ws; ws += (size_t)NBF * CAP * sizeof(unsigned int);

    hipMemsetAsync(cursor, 0, NBF * sizeof(int), stream);

    k_scatter<<<SC_BLOCKS, 1024, 0, stream>>>(row, col, cursor, pairs);
    k_gemm<<<LIN_BLOCKS, 256, 0, stream>>>(x, Wm, bm, Wr, br, Mh, es, out);
    k_aggregate<<<NBF, 512, 0, stream>>>(pairs, cursor, es,
                                         (const half4*)Mh, out);
}

// Round 8
// 164.695 us; speedup vs baseline: 4.8901x; 4.8901x over previous
//
#include <hip/hip_runtime.h>
#include <math.h>

#define N_NODES 100000
#define DIM 64
#define N_EDGES 1600000

#define NBF 782         // fine buckets: col >> 7 (ceil(100000/128) = 782)
#define BK_NODES 128
#define CAP 3072        // per-bucket slab capacity (mean 2046, sigma ~45)

#define SC_CHUNK 8192
#define SC_BLOCKS ((N_EDGES + SC_CHUNK - 1) / SC_CHUNK)  // 196

#define HB 128          // histogram blocks inside phase1
#define LIN_BLOCKS 1563 // ceil(6250 waves / 4 per block); 16 rows/wave
#define P1_BLOCKS (HB + LIN_BLOCKS)

typedef _Float16 half8 __attribute__((ext_vector_type(8)));
typedef _Float16 half4 __attribute__((ext_vector_type(4)));
typedef float f32x4 __attribute__((ext_vector_type(4)));

// ---------------------------------------------------------------------------
// Phase 1 (block-specialized):
//   blocks [0, HB): fine histogram of col>>7 with LDS privatization
//   blocks [HB, ..): MFMA f16 GEMM [16 x 64] @ [64 x 128] per wave
//     C cols 0..63  -> Mh (f16) = x@Wm + bm ; es = exp(mean_row(M))
//     C cols 64..127-> out (f32) = x@Wr + br
// ---------------------------------------------------------------------------
__global__ __launch_bounds__(256) void k_phase1(
        const float* __restrict__ x,
        const float* __restrict__ Wm, const float* __restrict__ bm,
        const float* __restrict__ Wr, const float* __restrict__ br,
        const int* __restrict__ col, int* __restrict__ hist,
        _Float16* __restrict__ Mh, float* __restrict__ es,
        float* __restrict__ out) {
    __shared__ int cnt[NBF];
    if (blockIdx.x < HB) {
        for (int i = threadIdx.x; i < NBF; i += 256) cnt[i] = 0;
        __syncthreads();
        for (int e = blockIdx.x * 256 + threadIdx.x; e < N_EDGES; e += HB * 256)
            atomicAdd(&cnt[col[e] >> 7], 1);
        __syncthreads();
        for (int i = threadIdx.x; i < NBF; i += 256)
            if (cnt[i]) atomicAdd(&hist[i], cnt[i]);
        return;
    }

    const int wave = (blockIdx.x - HB) * 4 + (threadIdx.x >> 6);
    if (wave >= N_NODES / 16) return;
    const int lane = threadIdx.x & 63;
    const int quad = lane >> 4;
    const int l15 = lane & 15;
    const int row0 = wave * 16;

    half8 bfrag[8][2];
#pragma unroll
    for (int ct = 0; ct < 8; ++ct) {
        const float* W = (ct < 4) ? Wm : Wr;
        const int c = (ct & 3) * 16 + l15;
#pragma unroll
        for (int kc = 0; kc < 2; ++kc) {
            half8 f;
#pragma unroll
            for (int j = 0; j < 8; ++j)
                f[j] = (_Float16)W[(kc * 32 + quad * 8 + j) * DIM + c];
            bfrag[ct][kc] = f;
        }
    }

    half8 afrag[2];
#pragma unroll
    for (int kc = 0; kc < 2; ++kc) {
        const float* xp = x + (size_t)(row0 + l15) * DIM + kc * 32 + quad * 8;
        const float4 x0 = *(const float4*)xp;
        const float4 x1 = *(const float4*)(xp + 4);
        half8 f;
        f[0] = (_Float16)x0.x; f[1] = (_Float16)x0.y;
        f[2] = (_Float16)x0.z; f[3] = (_Float16)x0.w;
        f[4] = (_Float16)x1.x; f[5] = (_Float16)x1.y;
        f[6] = (_Float16)x1.z; f[7] = (_Float16)x1.w;
        afrag[kc] = f;
    }

    f32x4 acc[8];
#pragma unroll
    for (int ct = 0; ct < 8; ++ct) {
        f32x4 a = {0.f, 0.f, 0.f, 0.f};
        a = __builtin_amdgcn_mfma_f32_16x16x32_f16(afrag[0], bfrag[ct][0], a, 0, 0, 0);
        a = __builtin_amdgcn_mfma_f32_16x16x32_f16(afrag[1], bfrag[ct][1], a, 0, 0, 0);
        acc[ct] = a;
    }

    float rsum[4] = {0.f, 0.f, 0.f, 0.f};
#pragma unroll
    for (int ct = 0; ct < 8; ++ct) {
        const float bias = (ct < 4) ? bm[(ct & 3) * 16 + l15]
                                    : br[(ct & 3) * 16 + l15];
#pragma unroll
        for (int r = 0; r < 4; ++r) {
            const float v = acc[ct][r] + bias;
            const size_t idx = (size_t)(row0 + quad * 4 + r) * DIM + (ct & 3) * 16 + l15;
            if (ct < 4) {
                Mh[idx] = (_Float16)v;
                rsum[r] += v;
            } else {
                out[idx] = v;
            }
        }
    }
#pragma unroll
    for (int o = 1; o <= 8; o <<= 1) {
#pragma unroll
        for (int r = 0; r < 4; ++r) rsum[r] += __shfl_xor(rsum[r], o, 64);
    }
    if (l15 == 0) {
#pragma unroll
        for (int r = 0; r < 4; ++r)
            es[row0 + quad * 4 + r] = __expf(rsum[r] * (1.0f / DIM));
    }
}

// ---------------------------------------------------------------------------
// Scan the 782-bin fine histogram -> working cursors (bucket fill counts are
// re-derived in bucket_gather from cursor deltas... we store cursors zeroed
// at slab-relative 0; each bucket's slab is [bk*CAP, ...]).
// Cursor here counts per-bucket fill level, starting at 0.
// ---------------------------------------------------------------------------
// (no scan needed: slabs are padded; cursor[b] just counts fills)

// ---------------------------------------------------------------------------
// Scatter: each 1024-thread block counting-sorts its 8192-edge chunk by fine
// bucket in LDS, reserves one range per nonzero bin via aggregated atomic on
// cursor[b] (slab-relative), writes packed edges ((row<<7)|(col&127)) into
// the bucket's padded slab.
// ---------------------------------------------------------------------------
__global__ __launch_bounds__(1024) void k_scatter(
        const int* __restrict__ row, const int* __restrict__ col,
        int* __restrict__ cursor, unsigned int* __restrict__ pairs) {
    __shared__ int cnt[NBF];
    __shared__ int base_l[NBF];
    __shared__ int base_g[NBF];
    __shared__ int sd[1024];
    __shared__ unsigned int stage[SC_CHUNK];
    __shared__ unsigned short stage_bk[SC_CHUNK];

    const int t = threadIdx.x;
    const int start = blockIdx.x * SC_CHUNK;
    const int mEnd = min(N_EDGES, start + SC_CHUNK);

    for (int i = t; i < NBF; i += 1024) cnt[i] = 0;
    __syncthreads();

    int rr[8], cc[8], lr[8];
#pragma unroll
    for (int k = 0; k < 8; ++k) {
        const int idx = start + k * 1024 + t;
        if (idx < mEnd) {
            cc[k] = col[idx];
            rr[k] = row[idx];
            lr[k] = atomicAdd(&cnt[cc[k] >> 7], 1);
        }
    }
    __syncthreads();

    const int v = (t < NBF) ? cnt[t] : 0;
    sd[t] = v;
    __syncthreads();
    for (int o = 1; o < 1024; o <<= 1) {
        const int add = (t >= o) ? sd[t - o] : 0;
        __syncthreads();
        sd[t] += add;
        __syncthreads();
    }
    if (t < NBF) {
        base_l[t] = sd[t] - v;
        if (v > 0) base_g[t] = atomicAdd(&cursor[t], v);
    }
    __syncthreads();

#pragma unroll
    for (int k = 0; k < 8; ++k) {
        const int idx = start + k * 1024 + t;
        if (idx < mEnd) {
            const int bk = cc[k] >> 7;
            const int slot = base_l[bk] + lr[k];
            stage[slot] = ((unsigned int)rr[k] << 7) | (unsigned int)(cc[k] & 127);
            stage_bk[slot] = (unsigned short)bk;
        }
    }
    __syncthreads();

    const int m = mEnd - start;
    for (int i = t; i < m; i += 1024) {
        const int bk = stage_bk[i];
        const int gslot = base_g[bk] + (i - base_l[bk]);
        if (gslot < CAP) pairs[(size_t)bk * CAP + gslot] = stage[i];
    }
}

// ---------------------------------------------------------------------------
// Bucket gather: one 512-thread block per fine bucket (128 dst nodes).
// 1) counting-sort the bucket's edges by local dst into LDS (no global csr).
// 2) each 16-lane group accumulates contiguous same-dst runs in registers
//    (atomic-free), 2-edge unroll for ILP, then RMWs out[dst] once.
// ---------------------------------------------------------------------------
__global__ __launch_bounds__(512) void k_bucket_gather(
        const unsigned int* __restrict__ pairs, const int* __restrict__ cursor,
        const float* __restrict__ es, const half4* __restrict__ Mh4,
        float4* __restrict__ out4) {
    __shared__ unsigned int sorted[CAP];      // 12 KB
    __shared__ int cnt[BK_NODES];
    __shared__ int off[BK_NODES];
    const int b = blockIdx.x;
    const int t = threadIdx.x;
    const int m = min(cursor[b], CAP);
    const size_t base = (size_t)b * CAP;

    if (t < BK_NODES) cnt[t] = 0;
    __syncthreads();

    // load + count + rank (<=6 edges per thread in registers)
    unsigned int pk[6];
    int rk[6];
#pragma unroll
    for (int k = 0; k < 6; ++k) {
        const int i = k * 512 + t;
        if (i < m) {
            pk[k] = pairs[base + i];
            rk[k] = atomicAdd(&cnt[pk[k] & 127u], 1);
        }
    }
    __syncthreads();

    // exclusive scan of 128 counts (first 128 threads, Hillis-Steele)
    int v = 0;
    if (t < BK_NODES) {
        v = cnt[t];
        off[t] = v;
    }
    __syncthreads();
    for (int o = 1; o < BK_NODES; o <<= 1) {
        int add = 0;
        if (t < BK_NODES && t >= o) add = off[t - o];
        __syncthreads();
        if (t < BK_NODES) off[t] += add;
        __syncthreads();
    }
    if (t < BK_NODES) off[t] -= v;  // exclusive
    __syncthreads();

    // place into sorted order
#pragma unroll
    for (int k = 0; k < 6; ++k) {
        const int i = k * 512 + t;
        if (i < m) sorted[off[pk[k] & 127u] + rk[k]] = pk[k];
    }
    __syncthreads();

    // accumulate: group g handles local dsts g, g+32, g+64, g+96
    const int g = t >> 4;
    const int gl = t & 15;
    for (int c = g; c < BK_NODES; c += 32) {
        const int node = b * BK_NODES + c;
        if (node >= N_NODES) break;
        const int s0i = off[c];
        const int len = cnt[c];
        if (len == 0) continue;

        float a0x = 0.f, a0y = 0.f, a0z = 0.f, a0w = 0.f, l0 = 0.f;
        float a1x = 0.f, a1y = 0.f, a1z = 0.f, a1w = 0.f, l1 = 0.f;
        int j = 0;
        for (; j + 1 < len; j += 2) {
            const int s0 = (int)(sorted[s0i + j] >> 7);
            const int s1 = (int)(sorted[s0i + j + 1] >> 7);
            const float w0 = es[s0];
            const float w1 = es[s1];
            const half4 m0 = Mh4[(size_t)s0 * 16 + gl];
            const half4 m1 = Mh4[(size_t)s1 * 16 + gl];
            l0 += w0; l1 += w1;
            a0x = fmaf(w0, (float)m0[0], a0x); a0y = fmaf(w0, (float)m0[1], a0y);
            a0z = fmaf(w0, (float)m0[2], a0z); a0w = fmaf(w0, (float)m0[3], a0w);
            a1x = fmaf(w1, (float)m1[0], a1x); a1y = fmaf(w1, (float)m1[1], a1y);
            a1z = fmaf(w1, (float)m1[2], a1z); a1w = fmaf(w1, (float)m1[3], a1w);
        }
        if (j < len) {
            const int s0 = (int)(sorted[s0i + j] >> 7);
            const float w0 = es[s0];
            const half4 m0 = Mh4[(size_t)s0 * 16 + gl];
            l0 += w0;
            a0x = fmaf(w0, (float)m0[0], a0x); a0y = fmaf(w0, (float)m0[1], a0y);
            a0z = fmaf(w0, (float)m0[2], a0z); a0w = fmaf(w0, (float)m0[3], a0w);
        }
        const float inv = 1.0f / (l0 + l1);
        float4 r = out4[(size_t)node * 16 + gl];
        r.x = fmaf(a0x + a1x, inv, r.x);
        r.y = fmaf(a0y + a1y, inv, r.y);
        r.z = fmaf(a0z + a1z, inv, r.z);
        r.w = fmaf(a0w + a1w, inv, r.w);
        out4[(size_t)node * 16 + gl] = r;
    }
}

// ---------------------------------------------------------------------------
extern "C" void kernel_launch(void* const* d_in, const int* in_sizes, int n_in,
                              void* d_out, int out_size, void* d_ws, size_t ws_size,
                              hipStream_t stream) {
    const float* x  = (const float*)d_in[0];
    const int*   ei = (const int*)d_in[1];
    const float* Wm = (const float*)d_in[2];
    const float* bm = (const float*)d_in[3];
    const float* Wr = (const float*)d_in[4];
    const float* br = (const float*)d_in[5];
    float* out = (float*)d_out;
    const int* row = ei;            // edge_index[0]
    const int* col = ei + N_EDGES;  // edge_index[1]

    char* ws = (char*)d_ws;
    _Float16* Mh    = (_Float16*)ws;     ws += (size_t)N_NODES * DIM * sizeof(_Float16);
    float* es       = (float*)ws;        ws += (size_t)N_NODES * sizeof(float);
    int* hist       = (int*)ws;          ws += (size_t)1024 * sizeof(int);
    int* cursor     = (int*)ws;          ws += (size_t)1024 * sizeof(int);
    unsigned int* pairs = (unsigned int*)ws; ws += (size_t)NBF * CAP * sizeof(unsigned int);

    hipMemsetAsync(cursor, 0, NBF * sizeof(int), stream);

    k_phase1<<<P1_BLOCKS, 256, 0, stream>>>(x, Wm, bm, Wr, br,
                                            col, hist, Mh, es, out);
    k_scatter<<<SC_BLOCKS, 1024, 0, stream>>>(row, col, cursor, pairs);
    k_bucket_gather<<<NBF, 512, 0, stream>>>(pairs, cursor, es,
                                             (const half4*)Mh, (float4*)out);
}

// Round 9
// 157.305 us; speedup vs baseline: 5.1198x; 1.0470x over previous
//
#include <hip/hip_runtime.h>
#include <math.h>

#define N_NODES 100000
#define DIM 64
#define N_EDGES 1600000

#define NBF 782         // fine buckets: col >> 7 (ceil(100000/128) = 782)
#define BK_NODES 128
#define CAP 3072        // per-bucket slab capacity (mean 2046, sigma ~45)

#define SC_CHUNK 8192
#define SC_BLOCKS ((N_EDGES + SC_CHUNK - 1) / SC_CHUNK)  // 196

#define GEMM_BLOCKS ((N_NODES / 16 + 15) / 16)  // 391 blocks x 16 waves
#define PH_BLOCKS (SC_BLOCKS + GEMM_BLOCKS)     // 587

typedef _Float16 half8 __attribute__((ext_vector_type(8)));
typedef _Float16 half4 __attribute__((ext_vector_type(4)));
typedef float f32x4 __attribute__((ext_vector_type(4)));

// ---------------------------------------------------------------------------
// Fused phase (block-specialized, 1024 threads):
//   blocks [0, SC_BLOCKS): scatter — counting-sort 8192-edge chunk by fine
//     bucket in LDS, reserve slab ranges via aggregated atomics, write packed
//     edges ((row<<7)|(col&127)) into padded slabs.
//   blocks [SC_BLOCKS, ..): MFMA f16 GEMM [16 x 64] @ [64 x 128] per wave.
//     C cols 0..63  -> Mh (f16) = x@Wm + bm ; es = exp(mean_row(M))
//     C cols 64..127-> out (f32) = x@Wr + br
// ---------------------------------------------------------------------------
__global__ __launch_bounds__(1024) void k_phase(
        const float* __restrict__ x,
        const float* __restrict__ Wm, const float* __restrict__ bm,
        const float* __restrict__ Wr, const float* __restrict__ br,
        const int* __restrict__ row, const int* __restrict__ col,
        int* __restrict__ cursor, unsigned int* __restrict__ pairs,
        _Float16* __restrict__ Mh, float* __restrict__ es,
        float* __restrict__ out) {
    __shared__ int cnt[NBF];
    __shared__ int base_l[NBF];
    __shared__ int base_g[NBF];
    __shared__ int wsum[16];
    __shared__ unsigned int stage[SC_CHUNK];
    __shared__ unsigned short stage_bk[SC_CHUNK];

    const int t = threadIdx.x;
    const int lane = t & 63;
    const int wid = t >> 6;

    if (blockIdx.x < SC_BLOCKS) {
        const int start = blockIdx.x * SC_CHUNK;
        const int mEnd = min(N_EDGES, start + SC_CHUNK);

        for (int i = t; i < NBF; i += 1024) cnt[i] = 0;
        __syncthreads();

        int rr[8], cc[8], lr[8];
#pragma unroll
        for (int k = 0; k < 8; ++k) {
            const int idx = start + k * 1024 + t;
            if (idx < mEnd) {
                cc[k] = col[idx];
                rr[k] = row[idx];
                lr[k] = atomicAdd(&cnt[cc[k] >> 7], 1);
            }
        }
        __syncthreads();

        // two-level exclusive scan over cnt[0..NBF) using wave shfl scans
        const int v = (t < NBF) ? cnt[t] : 0;
        int inc = v;
#pragma unroll
        for (int o = 1; o < 64; o <<= 1) {
            const int u = __shfl_up(inc, o, 64);
            if (lane >= o) inc += u;
        }
        if (lane == 63) wsum[wid] = inc;
        __syncthreads();
        if (wid == 0) {
            const int wv = (lane < 16) ? wsum[lane] : 0;
            int winc = wv;
#pragma unroll
            for (int o = 1; o < 16; o <<= 1) {
                const int u = __shfl_up(winc, o, 64);
                if (lane >= o) winc += u;
            }
            if (lane < 16) wsum[lane] = winc - wv;  // exclusive wave offsets
        }
        __syncthreads();
        if (t < NBF) {
            base_l[t] = inc - v + wsum[wid];  // exclusive scan value
            if (v > 0) base_g[t] = atomicAdd(&cursor[t], v);
        }
        __syncthreads();

#pragma unroll
        for (int k = 0; k < 8; ++k) {
            const int idx = start + k * 1024 + t;
            if (idx < mEnd) {
                const int bk = cc[k] >> 7;
                const int slot = base_l[bk] + lr[k];
                stage[slot] = ((unsigned int)rr[k] << 7) | (unsigned int)(cc[k] & 127);
                stage_bk[slot] = (unsigned short)bk;
            }
        }
        __syncthreads();

        const int m = mEnd - start;
        for (int i = t; i < m; i += 1024) {
            const int bk = stage_bk[i];
            const int gslot = base_g[bk] + (i - base_l[bk]);
            if (gslot < CAP) pairs[(size_t)bk * CAP + gslot] = stage[i];
        }
        return;
    }

    // ---- GEMM branch ----
    const int wave = (blockIdx.x - SC_BLOCKS) * 16 + wid;
    if (wave >= N_NODES / 16) return;
    const int quad = lane >> 4;
    const int l15 = lane & 15;
    const int row0 = wave * 16;

    half8 bfrag[8][2];
#pragma unroll
    for (int ct = 0; ct < 8; ++ct) {
        const float* W = (ct < 4) ? Wm : Wr;
        const int c = (ct & 3) * 16 + l15;
#pragma unroll
        for (int kc = 0; kc < 2; ++kc) {
            half8 f;
#pragma unroll
            for (int j = 0; j < 8; ++j)
                f[j] = (_Float16)W[(kc * 32 + quad * 8 + j) * DIM + c];
            bfrag[ct][kc] = f;
        }
    }

    half8 afrag[2];
#pragma unroll
    for (int kc = 0; kc < 2; ++kc) {
        const float* xp = x + (size_t)(row0 + l15) * DIM + kc * 32 + quad * 8;
        const float4 x0 = *(const float4*)xp;
        const float4 x1 = *(const float4*)(xp + 4);
        half8 f;
        f[0] = (_Float16)x0.x; f[1] = (_Float16)x0.y;
        f[2] = (_Float16)x0.z; f[3] = (_Float16)x0.w;
        f[4] = (_Float16)x1.x; f[5] = (_Float16)x1.y;
        f[6] = (_Float16)x1.z; f[7] = (_Float16)x1.w;
        afrag[kc] = f;
    }

    f32x4 acc[8];
#pragma unroll
    for (int ct = 0; ct < 8; ++ct) {
        f32x4 a = {0.f, 0.f, 0.f, 0.f};
        a = __builtin_amdgcn_mfma_f32_16x16x32_f16(afrag[0], bfrag[ct][0], a, 0, 0, 0);
        a = __builtin_amdgcn_mfma_f32_16x16x32_f16(afrag[1], bfrag[ct][1], a, 0, 0, 0);
        acc[ct] = a;
    }

    float rsum[4] = {0.f, 0.f, 0.f, 0.f};
#pragma unroll
    for (int ct = 0; ct < 8; ++ct) {
        const float bias = (ct < 4) ? bm[(ct & 3) * 16 + l15]
                                    : br[(ct & 3) * 16 + l15];
#pragma unroll
        for (int r = 0; r < 4; ++r) {
            const float v = acc[ct][r] + bias;
            const size_t idx = (size_t)(row0 + quad * 4 + r) * DIM + (ct & 3) * 16 + l15;
            if (ct < 4) {
                Mh[idx] = (_Float16)v;
                rsum[r] += v;
            } else {
                out[idx] = v;
            }
        }
    }
#pragma unroll
    for (int o = 1; o <= 8; o <<= 1) {
#pragma unroll
        for (int r = 0; r < 4; ++r) rsum[r] += __shfl_xor(rsum[r], o, 64);
    }
    if (l15 == 0) {
#pragma unroll
        for (int r = 0; r < 4; ++r)
            es[row0 + quad * 4 + r] = __expf(rsum[r] * (1.0f / DIM));
    }
}

// ---------------------------------------------------------------------------
// Bucket gather: one 512-thread block per fine bucket (128 dst nodes).
// 1) counting-sort the bucket's edges by local dst into LDS.
// 2) each 16-lane group accumulates contiguous same-dst runs in registers
//    (atomic-free), 2-edge unroll for ILP, then RMWs out[dst] once.
// ---------------------------------------------------------------------------
__global__ __launch_bounds__(512) void k_bucket_gather(
        const unsigned int* __restrict__ pairs, const int* __restrict__ cursor,
        const float* __restrict__ es, const half4* __restrict__ Mh4,
        float4* __restrict__ out4) {
    __shared__ unsigned int sorted[CAP];      // 12 KB
    __shared__ int cnt[BK_NODES];
    __shared__ int off[BK_NODES];
    const int b = blockIdx.x;
    const int t = threadIdx.x;
    const int m = min(cursor[b], CAP);
    const size_t base = (size_t)b * CAP;

    if (t < BK_NODES) cnt[t] = 0;
    __syncthreads();

    unsigned int pk[6];
    int rk[6];
#pragma unroll
    for (int k = 0; k < 6; ++k) {
        const int i = k * 512 + t;
        if (i < m) {
            pk[k] = pairs[base + i];
            rk[k] = atomicAdd(&cnt[pk[k] & 127u], 1);
        }
    }
    __syncthreads();

    int v = 0;
    if (t < BK_NODES) {
        v = cnt[t];
        off[t] = v;
    }
    __syncthreads();
    for (int o = 1; o < BK_NODES; o <<= 1) {
        int add = 0;
        if (t < BK_NODES && t >= o) add = off[t - o];
        __syncthreads();
        if (t < BK_NODES) off[t] += add;
        __syncthreads();
    }
    if (t < BK_NODES) off[t] -= v;  // exclusive
    __syncthreads();

#pragma unroll
    for (int k = 0; k < 6; ++k) {
        const int i = k * 512 + t;
        if (i < m) sorted[off[pk[k] & 127u] + rk[k]] = pk[k];
    }
    __syncthreads();

    const int g = t >> 4;
    const int gl = t & 15;
    for (int c = g; c < BK_NODES; c += 32) {
        const int node = b * BK_NODES + c;
        if (node >= N_NODES) break;
        const int s0i = off[c];
        const int len = cnt[c];
        if (len == 0) continue;

        float a0x = 0.f, a0y = 0.f, a0z = 0.f, a0w = 0.f, l0 = 0.f;
        float a1x = 0.f, a1y = 0.f, a1z = 0.f, a1w = 0.f, l1 = 0.f;
        int j = 0;
        for (; j + 1 < len; j += 2) {
            const int s0 = (int)(sorted[s0i + j] >> 7);
            const int s1 = (int)(sorted[s0i + j + 1] >> 7);
            const float w0 = es[s0];
            const float w1 = es[s1];
            const half4 m0 = Mh4[(size_t)s0 * 16 + gl];
            const half4 m1 = Mh4[(size_t)s1 * 16 + gl];
            l0 += w0; l1 += w1;
            a0x = fmaf(w0, (float)m0[0], a0x); a0y = fmaf(w0, (float)m0[1], a0y);
            a0z = fmaf(w0, (float)m0[2], a0z); a0w = fmaf(w0, (float)m0[3], a0w);
            a1x = fmaf(w1, (float)m1[0], a1x); a1y = fmaf(w1, (float)m1[1], a1y);
            a1z = fmaf(w1, (float)m1[2], a1z); a1w = fmaf(w1, (float)m1[3], a1w);
        }
        if (j < len) {
            const int s0 = (int)(sorted[s0i + j] >> 7);
            const float w0 = es[s0];
            const half4 m0 = Mh4[(size_t)s0 * 16 + gl];
            l0 += w0;
            a0x = fmaf(w0, (float)m0[0], a0x); a0y = fmaf(w0, (float)m0[1], a0y);
            a0z = fmaf(w0, (float)m0[2], a0z); a0w = fmaf(w0, (float)m0[3], a0w);
        }
        const float inv = 1.0f / (l0 + l1);
        float4 r = out4[(size_t)node * 16 + gl];
        r.x = fmaf(a0x + a1x, inv, r.x);
        r.y = fmaf(a0y + a1y, inv, r.y);
        r.z = fmaf(a0z + a1z, inv, r.z);
        r.w = fmaf(a0w + a1w, inv, r.w);
        out4[(size_t)node * 16 + gl] = r;
    }
}

// ---------------------------------------------------------------------------
extern "C" void kernel_launch(void* const* d_in, const int* in_sizes, int n_in,
                              void* d_out, int out_size, void* d_ws, size_t ws_size,
                              hipStream_t stream) {
    const float* x  = (const float*)d_in[0];
    const int*   ei = (const int*)d_in[1];
    const float* Wm = (const float*)d_in[2];
    const float* bm = (const float*)d_in[3];
    const float* Wr = (const float*)d_in[4];
    const float* br = (const float*)d_in[5];
    float* out = (float*)d_out;
    const int* row = ei;            // edge_index[0]
    const int* col = ei + N_EDGES;  // edge_index[1]

    char* ws = (char*)d_ws;
    _Float16* Mh    = (_Float16*)ws;     ws += (size_t)N_NODES * DIM * sizeof(_Float16);
    float* es       = (float*)ws;        ws += (size_t)N_NODES * sizeof(float);
    int* cursor     = (int*)ws;          ws += (size_t)1024 * sizeof(int);
    unsigned int* pairs = (unsigned int*)ws; ws += (size_t)NBF * CAP * sizeof(unsigned int);

    hipMemsetAsync(cursor, 0, NBF * sizeof(int), stream);

    k_phase<<<PH_BLOCKS, 1024, 0, stream>>>(x, Wm, bm, Wr, br, row, col,
                                            cursor, pairs, Mh, es, out);
    k_bucket_gather<<<NBF, 512, 0, stream>>>(pairs, cursor, es,
                                             (const half4*)Mh, (float4*)out);
}